// Round 24
// baseline (111.612 us; speedup 1.0000x reference)
//
#include <hip/hip_runtime.h>

// All tensors float32. Math structure exploited:
//  - softmax over axis of size 1 == 1.0 -> attn all-ones, Wa/ba dead.
//  - weighted = row-sum of tanh(agg), broadcast over COLUMNS (N==D quirk).
//  - lig_p = nf@Wl.T + const  ->  x0[h,i,j] = PL[i,h] + PR[j,h] + c[h]
//  - conv1 is LINEAR in rank-structured x0: y1_pre = U[xc][y] + V[yc][x] + K'.
//  - ROUND-24: P moved OUT of gnn (side-path cost gnn ~26us: register/LDS
//    pressure on makespan-gating blocks) into a WIDE pk_kernel: 128 P-blocks
//    x 16 rows (64KB cold nf each -> ~10us at per-CU in-flight limit; r21-22
//    proved 32 blocks = 42us was concurrency, not structure). Waves own K=128
//    chunks barrier-free (r20-verified fragments) + one LDS reduction.
//    partial_c + w2pack ride pk's grid; pp2 = uv + kfin role. gnn = clean
//    r18 version. conv = round-16 verbatim. 4 dispatches.

typedef _Float16 half8 __attribute__((ext_vector_type(8)));
typedef _Float16 half4 __attribute__((ext_vector_type(4)));
typedef float    f32x4 __attribute__((ext_vector_type(4)));

__device__ __forceinline__ short f2h_bits(float f){
    _Float16 h = (_Float16)f;          // RNE
    return __builtin_bit_cast(short, h);
}
__device__ __forceinline__ half8 pack2(const float4& x, const float4& y){
    half8 r;
    r[0] = (_Float16)x.x; r[1] = (_Float16)x.y;
    r[2] = (_Float16)x.z; r[3] = (_Float16)x.w;
    r[4] = (_Float16)y.x; r[5] = (_Float16)y.y;
    r[6] = (_Float16)y.z; r[7] = (_Float16)y.w;
    return r;
}
__device__ __forceinline__ float tanh_fast(float x){
    float e = __expf(2.f * x);
    return 1.f - 2.f / (e + 1.f);
}

// ci-block swizzle (round-4 verified layout)
#define SWZ(c) ((((c) >> 1) & 3) << 3)

// ---------------------------------------------------------------------------
// K1 (MFMA): gnn, BM=128/BN=64/BK=64, 512 thr, depth-2 reg prefetch.
// grid (8,16,2). (clean r18/r20 version, verbatim)
// ---------------------------------------------------------------------------
#define GNN_LOAD(AV, BV, KBN) {                                              \
    const int kbn_ = (KBN) & 2047;                                           \
    const float* Asrc_ = (kbn_ < 1024) ? A0 : A1;                            \
    const float* Bsrc_ = (kbn_ < 1024) ? Wn : We;                            \
    const int kk_ = kbn_ & 1023;                                             \
    const float* ap_ = Asrc_ + (size_t)(j0 + arow) * 1024 + kk_ + akc;       \
    const float* bp_ = Bsrc_ + (size_t)(d0 + brow) * 1024 + kk_ + bkc;       \
    AV[0] = *reinterpret_cast<const float4*>(ap_);                           \
    AV[1] = *reinterpret_cast<const float4*>(ap_ + 4);                       \
    AV[2] = *reinterpret_cast<const float4*>(ap_ + 8);                       \
    AV[3] = *reinterpret_cast<const float4*>(ap_ + 12);                      \
    BV[0] = *reinterpret_cast<const float4*>(bp_);                           \
    BV[1] = *reinterpret_cast<const float4*>(bp_ + 4);                       \
}

#define GNN_STAGE(AV, BV) {                                                  \
    const int ga_ = (t & 3) * 2;                                             \
    const int sa_ = arow & 7;                                                \
    *reinterpret_cast<half8*>(&As[arow * 64 + ((ga_    ) ^ sa_) * 8]) = pack2(AV[0], AV[1]); \
    *reinterpret_cast<half8*>(&As[arow * 64 + ((ga_ + 1) ^ sa_) * 8]) = pack2(AV[2], AV[3]); \
    *reinterpret_cast<half8*>(&Bs[brow * 64 + ((t & 7) ^ (brow & 7)) * 8]) = pack2(BV[0], BV[1]); \
}

#define GNN_MFMA() {                                                         \
    _Pragma("unroll")                                                        \
    for (int ks = 0; ks < 2; ++ks){                                          \
        half8 Af[2], Bf[2];                                                  \
        _Pragma("unroll")                                                    \
        for (int m = 0; m < 2; ++m){                                         \
            int row = wm * 32 + m * 16 + lr;                                 \
            int g   = ((ks * 4 + lg) ^ (row & 7)) * 8;                       \
            Af[m] = *reinterpret_cast<const half8*>(&As[row * 64 + g]);      \
        }                                                                    \
        _Pragma("unroll")                                                    \
        for (int n = 0; n < 2; ++n){                                         \
            int col = wn * 32 + n * 16 + lr;                                 \
            int g   = ((ks * 4 + lg) ^ (col & 7)) * 8;                       \
            Bf[n] = *reinterpret_cast<const half8*>(&Bs[col * 64 + g]);      \
        }                                                                    \
        _Pragma("unroll")                                                    \
        for (int m = 0; m < 2; ++m)                                          \
            _Pragma("unroll")                                                \
            for (int n = 0; n < 2; ++n)                                      \
                acc[m][n] = __builtin_amdgcn_mfma_f32_16x16x32_f16(          \
                    Af[m], Bf[n], acc[m][n], 0, 0, 0);                       \
    }                                                                        \
}

__global__ __launch_bounds__(512) void gnn_kernel(
    const float* __restrict__ lig_nf, const float* __restrict__ lig_ef,
    const float* __restrict__ rec_nf, const float* __restrict__ rec_ef,
    const float* __restrict__ Wn, const float* __restrict__ We,
    const float* __restrict__ bn, const float* __restrict__ be,
    float* __restrict__ part)   // [2][16][1024]
{
    __shared__ __attribute__((aligned(16))) short As[128 * 64];
    __shared__ __attribute__((aligned(16))) short Bs[64 * 64];
    __shared__ float red[128][2];

    const int t  = threadIdx.x;
    const int cx = blockIdx.z;
    const float* A0 = cx ? rec_nf : lig_nf;
    const float* A1 = cx ? rec_ef : lig_ef;
    const int j0 = blockIdx.x * 128;
    const int d0 = blockIdx.y * 64;

    const int wid  = t >> 6;
    const int wm   = wid >> 1;
    const int wn   = wid & 1;
    const int lane = t & 63;
    const int lr   = lane & 15;
    const int lg   = lane >> 4;

    f32x4 acc[2][2];
    #pragma unroll
    for (int m = 0; m < 2; ++m)
        #pragma unroll
        for (int n = 0; n < 2; ++n)
            acc[m][n] = (f32x4){0.f, 0.f, 0.f, 0.f};

    const int arow = t >> 2;
    const int akc  = (t & 3) * 16;
    const int brow = t >> 3;
    const int bkc  = (t & 7) * 8;

    float4 avA[4], bvA[2], avB[4], bvB[2];
    GNN_LOAD(avA, bvA, 0);
    GNN_LOAD(avB, bvB, 64);

    for (int kb = 0; kb < 2048; kb += 128){
        __syncthreads();
        GNN_STAGE(avA, bvA);
        GNN_LOAD(avA, bvA, kb + 128);
        __syncthreads();
        GNN_MFMA();
        __syncthreads();
        GNN_STAGE(avB, bvB);
        GNN_LOAD(avB, bvB, kb + 192);
        __syncthreads();
        GNN_MFMA();
    }

    float rowsum[2][4];
    #pragma unroll
    for (int m = 0; m < 2; ++m)
        #pragma unroll
        for (int jj = 0; jj < 4; ++jj) rowsum[m][jj] = 0.f;
    #pragma unroll
    for (int n = 0; n < 2; ++n){
        int d = d0 + wn * 32 + n * 16 + lr;
        float bias = bn[d] + be[d];
        #pragma unroll
        for (int m = 0; m < 2; ++m)
            #pragma unroll
            for (int jj = 0; jj < 4; ++jj)
                rowsum[m][jj] += tanh_fast(acc[m][n][jj] + bias);
    }
    #pragma unroll
    for (int mask = 1; mask < 16; mask <<= 1)
        #pragma unroll
        for (int m = 0; m < 2; ++m)
            #pragma unroll
            for (int jj = 0; jj < 4; ++jj)
                rowsum[m][jj] += __shfl_xor(rowsum[m][jj], mask);
    __syncthreads();
    if (lr == 0){
        #pragma unroll
        for (int m = 0; m < 2; ++m)
            #pragma unroll
            for (int jj = 0; jj < 4; ++jj)
                red[wm * 32 + m * 16 + lg * 4 + jj][wn] = rowsum[m][jj];
    }
    __syncthreads();
    if (t < 128)
        part[(size_t)cx * 16384 + (size_t)blockIdx.y * 1024 + j0 + t]
            = red[t][0] + red[t][1];
}

// ---------------------------------------------------------------------------
// K2: pk_kernel. grid 145 x 512 thr.
//  roles 0..127 : P -- block handles 16 rows (cx = b>>6, r0 = (b&63)*16).
//                 Wave w owns K-chunk w*128..+128 (barrier-free MFMA), then
//                 one LDS reduction across waves -> Pw f16.
//  roles 128..143: partial_c (chunk q = role-128, 64 j's) -> cpart
//  role 144     : w2pack -> w2f16
// ---------------------------------------------------------------------------
__global__ __launch_bounds__(512) void pk_kernel(
    const float* __restrict__ lig_nf, const float* __restrict__ rec_nf,
    const float* __restrict__ W_hopi, const float* __restrict__ w2,
    const float* __restrict__ part,
    short* __restrict__ Pw, float* __restrict__ cpart,
    short* __restrict__ w2f16)
{
    __shared__ __attribute__((aligned(16))) char smem[16384];
    const int t = threadIdx.x;
    const int role = blockIdx.x;

    if (role < 128){
        float* red = reinterpret_cast<float*>(smem);   // [8][16][32] f32
        const int cx = role >> 6;
        const int r0 = (role & 63) * 16;
        const float* nf = cx ? rec_nf : lig_nf;
        const float* W  = W_hopi + (cx ? 1024 : 0);

        const int wid = t >> 6;
        const int lane = t & 63;
        const int lr = lane & 15;
        const int lg = lane >> 4;

        f32x4 pacc[2];
        pacc[0] = (f32x4){0.f, 0.f, 0.f, 0.f};
        pacc[1] = (f32x4){0.f, 0.f, 0.f, 0.f};

        const float* ap  = nf + (size_t)(r0 + lr) * 1024 + lg * 8;
        const float* b0  = W + (size_t)lr * 2048 + lg * 8;
        const float* b1p = W + (size_t)(16 + lr) * 2048 + lg * 8;
        const int kbase = wid * 128;

        #pragma unroll
        for (int ks = 0; ks < 4; ++ks){
            const int kb = kbase + ks * 32;
            half8 Af = pack2(*reinterpret_cast<const float4*>(ap + kb),
                             *reinterpret_cast<const float4*>(ap + kb + 4));
            half8 B0 = pack2(*reinterpret_cast<const float4*>(b0 + kb),
                             *reinterpret_cast<const float4*>(b0 + kb + 4));
            half8 B1 = pack2(*reinterpret_cast<const float4*>(b1p + kb),
                             *reinterpret_cast<const float4*>(b1p + kb + 4));
            pacc[0] = __builtin_amdgcn_mfma_f32_16x16x32_f16(Af, B0, pacc[0], 0, 0, 0);
            pacc[1] = __builtin_amdgcn_mfma_f32_16x16x32_f16(Af, B1, pacc[1], 0, 0, 0);
        }
        // partials -> LDS: value (row=lg*4+jj, h=n*16+lr) per wave
        #pragma unroll
        for (int n = 0; n < 2; ++n)
            #pragma unroll
            for (int jj = 0; jj < 4; ++jj)
                red[(wid * 16 + lg * 4 + jj) * 32 + n * 16 + lr] = pacc[n][jj];
        __syncthreads();
        // reduce 8 waves: thread t -> (row = t>>5, h = t&31)
        {
            const int row = t >> 5;
            const int h   = t & 31;
            float s = 0.f;
            #pragma unroll
            for (int w = 0; w < 8; ++w)
                s += red[(w * 16 + row) * 32 + h];
            Pw[(size_t)cx * 32768 + (size_t)(r0 + row) * 32 + h] = f2h_bits(s);
        }
        return;
    }

    if (role == 144){
        #pragma unroll
        for (int q = 0; q < 18; ++q){
            int e = t + q * 512;
            int co  = e / 288;
            int rem = e - co * 288;
            int ci  = rem / 9;
            int tap = rem - ci * 9;
            w2f16[(tap * 32 + co) * 32 + (ci ^ SWZ(co))] = f2h_bits(w2[e]);
        }
        return;
    }

    // ---------------- partial_c role (q = role-128, j in [q*64, q*64+64)) ----
    {
        float* ws_l = reinterpret_cast<float*>(smem);          // 64 f32
        float* ws_r = reinterpret_cast<float*>(smem + 256);    // 64 f32
        float* red  = reinterpret_cast<float*>(smem + 512);    // 512 f32

        const int q  = role - 128;
        const int jb = q * 64;

        if (t < 64){
            int j = jb + t;
            float sl = 0.f, sr = 0.f;
            #pragma unroll
            for (int b = 0; b < 16; ++b){
                sl += part[b * 1024 + j];
                sr += part[16384 + b * 1024 + j];
            }
            ws_l[t] = sl; ws_r[t] = sr;
        }
        __syncthreads();

        const int h = t >> 4;
        const int g = t & 15;
        const float* wl = W_hopi + (size_t)h * 2048 + jb + g * 4;
        const float* wr = wl + 1024;
        float4 a = *reinterpret_cast<const float4*>(wl);
        float4 b = *reinterpret_cast<const float4*>(wr);
        const float* l = &ws_l[g * 4];
        const float* r = &ws_r[g * 4];
        float s = l[0] * a.x + l[1] * a.y + l[2] * a.z + l[3] * a.w
                + r[0] * b.x + r[1] * b.y + r[2] * b.z + r[3] * b.w;
        red[t] = s;
        __syncthreads();
        if (t < 32){
            float tot = 0.f;
            #pragma unroll
            for (int gg = 0; gg < 16; ++gg) tot += red[t * 16 + gg];
            cpart[q * 32 + t] = tot;
        }
    }
}

// ---------------------------------------------------------------------------
// K3: pp2_kernel. grid 33 x 512 thr.
//  roles 0..31: uv (reads L2-hot Pw, writes U16/V16)
//  role 32    : kfin -- c[h] = b_hopi + sum cpart; Kp from unrolled w1 taps
// ---------------------------------------------------------------------------
__global__ __launch_bounds__(512) void pp2_kernel(
    const float* __restrict__ b_hopi,
    const float* __restrict__ w1, const float* __restrict__ b1,
    const short* __restrict__ Pw, const float* __restrict__ cpart,
    float* __restrict__ Kp, short* __restrict__ U16, short* __restrict__ V16)
{
    __shared__ __attribute__((aligned(16))) char smem[47232];
    const int t = threadIdx.x;
    const int role = blockIdx.x;

    if (role < 32){
        short* Pz = reinterpret_cast<short*>(smem);            // 66 x stride40
        short* Ws = reinterpret_cast<short*>(smem + 5376);     // 3x32 x stride104

        const int cx = role >> 4;
        const int r0 = (role & 15) * 64;
        short* O = cx ? V16 : U16;
        const short* Psrc = Pw + (size_t)cx * 32768;

        const int wid = t >> 6;
        const int lane = t & 63;
        const int lr = lane & 15;
        const int lg = lane >> 4;

        for (int idx = t; idx < 2112; idx += 512){
            int l = idx >> 5;
            int h = idx & 31;
            int gr = r0 - 1 + l;
            short v = 0;
            if ((unsigned)gr < 1024u) v = Psrc[(size_t)gr * 32 + h];
            Pz[l * 40 + h] = v;
        }

        #pragma unroll
        for (int q = 0; q < 2; ++q){
            int pr = t * 2 + q;
            int co = pr >> 5;
            int ci = pr & 31;
            const float* wp = w1 + co * 288 + ci * 9;
            float tap[9];
            #pragma unroll
            for (int e = 0; e < 9; ++e) tap[e] = wp[e];
            #pragma unroll
            for (int d = 0; d < 3; ++d){
                float ta, tb, tc;
                if (cx == 0){ ta = tap[d * 3 + 0]; tb = tap[d * 3 + 1]; tc = tap[d * 3 + 2]; }
                else        { ta = tap[0 + d];     tb = tap[3 + d];     tc = tap[6 + d]; }
                Ws[(0 * 32 + co) * 104 + d * 32 + ci] = f2h_bits(ta + tb + tc);
                Ws[(1 * 32 + co) * 104 + d * 32 + ci] = f2h_bits(tb + tc);
                Ws[(2 * 32 + co) * 104 + d * 32 + ci] = f2h_bits(ta + tb);
            }
        }
        __syncthreads();

        if (wid < 4){
            f32x4 uacc[3][2];
            #pragma unroll
            for (int cs = 0; cs < 3; ++cs)
                #pragma unroll
                for (int n = 0; n < 2; ++n)
                    uacc[cs][n] = (f32x4){0.f, 0.f, 0.f, 0.f};
            #pragma unroll
            for (int d = 0; d < 3; ++d){
                int ar = wid * 16 + lr;
                half8 Ap = *reinterpret_cast<const half8*>(
                    &Pz[(ar + d) * 40 + lg * 8]);
                #pragma unroll
                for (int cs = 0; cs < 3; ++cs)
                    #pragma unroll
                    for (int n = 0; n < 2; ++n){
                        half8 Bp = *reinterpret_cast<const half8*>(
                            &Ws[(cs * 32 + n * 16 + lr) * 104 + d * 32 + lg * 8]);
                        uacc[cs][n] = __builtin_amdgcn_mfma_f32_16x16x32_f16(
                            Ap, Bp, uacc[cs][n], 0, 0, 0);
                    }
            }
            #pragma unroll
            for (int cs = 0; cs < 3; ++cs)
                #pragma unroll
                for (int n = 0; n < 2; ++n)
                    #pragma unroll
                    for (int jj = 0; jj < 4; ++jj){
                        int grow = r0 + wid * 16 + lg * 4 + jj;
                        O[((size_t)(cs << 10) + grow) * 32 + n * 16 + lr]
                            = f2h_bits(uacc[cs][n][jj]);
                    }
        }
        return;
    }

    // ---------------- kfin role ----------------
    {
        float* cvs = reinterpret_cast<float*>(smem);           // 128 B
        float* w1s = reinterpret_cast<float*>(smem + 128);     // 36864 B

        #pragma unroll
        for (int q = 0; q < 5; ++q){
            int i4 = t + q * 512;
            if (i4 < 2304)
                *reinterpret_cast<float4*>(&w1s[i4 * 4]) =
                    *reinterpret_cast<const float4*>(w1 + i4 * 4);
        }
        if (t < 32){
            float tot = b_hopi[t];
            #pragma unroll
            for (int q = 0; q < 16; ++q) tot += cpart[q * 32 + t];
            cvs[t] = tot;
        }
        __syncthreads();
        for (int e = t; e < 288; e += 512){
            int co  = e & 31;
            int cse = e >> 5;
            int yc  = cse / 3, xc = cse - yc * 3;
            float sum = b1[co];
            for (int ci = 0; ci < 32; ++ci){
                const float* wp = &w1s[co * 288 + ci * 9];
                float t00 = wp[0], t01 = wp[1], t02 = wp[2];
                float t10 = wp[3], t11 = wp[4], t12 = wp[5];
                float t20 = wp[6], t21 = wp[7], t22 = wp[8];
                float r0v, r1v, r2v;
                if (xc == 0){ r0v = t00+t01+t02; r1v = t10+t11+t12; r2v = t20+t21+t22; }
                else if (xc == 1){ r0v = t01+t02; r1v = t11+t12; r2v = t21+t22; }
                else { r0v = t00+t01; r1v = t10+t11; r2v = t20+t21; }
                float wsum = (yc == 0) ? (r0v+r1v+r2v) : ((yc == 1) ? (r1v+r2v) : (r0v+r1v));
                sum = fmaf(cvs[ci], wsum, sum);
            }
            Kp[cse * 32 + co] = sum;
        }
    }
}

// ---------------------------------------------------------------------------
// K4: stage ys = relu(U+V+K') (interior fast path in packed f16), wB by uint4
// copy of prepacked w2f16, then conv2+relu+conv3 on f16 MFMA. LDS = 39,168 B.
// block 512, grid 64x64. (round-16 verbatim)
// ---------------------------------------------------------------------------
__global__ __launch_bounds__(512) void conv_kernel(
    const short* __restrict__ U16, const short* __restrict__ V16,
    const float* __restrict__ Kp, const short* __restrict__ w2f16,
    const float* __restrict__ b2,
    const float* __restrict__ w3, const float* __restrict__ b3,
    float* __restrict__ outp)
{
    __shared__ __attribute__((aligned(16))) short ys[18 * 18 * 32];
    __shared__ __attribute__((aligned(16))) short wB[9 * 32 * 32];

    const int t    = threadIdx.x;
    const int oy0  = blockIdx.y * 16;
    const int ox0  = blockIdx.x * 16;
    const int wid  = t >> 6;
    const int lane = t & 63;
    const int lr   = lane & 15;
    const int lg   = lane >> 4;

    {
        const uint4* src = reinterpret_cast<const uint4*>(w2f16);
        uint4* dst = reinterpret_cast<uint4*>(wB);
        #pragma unroll
        for (int e = t; e < 1152; e += 512)
            dst[e] = src[e];
    }
    const bool interior = (blockIdx.x >= 1) & (blockIdx.x <= 62) &
                          (blockIdx.y >= 1) & (blockIdx.y <= 62);
    if (interior){
        const int cp = (t & 7) * 4;
        half4 k00;
        {
            float4 kf = *reinterpret_cast<const float4*>(&Kp[cp]);
            k00[0] = (_Float16)kf.x; k00[1] = (_Float16)kf.y;
            k00[2] = (_Float16)kf.z; k00[3] = (_Float16)kf.w;
        }
        #pragma unroll
        for (int pass = 0; pass < 6; ++pass){
            int idx = t + pass * 512;
            if (idx < 2592){
                int po  = idx >> 3;
                int ryo = po / 18;
                int rxo = po - ryo * 18;
                int gy = oy0 - 1 + ryo, gx = ox0 - 1 + rxo;
                half4 u = *reinterpret_cast<const half4*>(&U16[gy * 32 + cp]);
                half4 v = *reinterpret_cast<const half4*>(&V16[gx * 32 + cp]);
                half4 r = u + v + k00;
                #pragma unroll
                for (int e = 0; e < 4; ++e)
                    r[e] = r[e] > (_Float16)0.f ? r[e] : (_Float16)0.f;
                *reinterpret_cast<half4*>(&ys[po * 32 + (cp ^ SWZ(rxo))]) = r;
            }
        }
    } else {
        #pragma unroll
        for (int pass = 0; pass < 6; ++pass){
            int idx = t + pass * 512;
            if (idx < 2592){
                int po  = idx >> 3;
                int cp  = (idx & 7) * 4;
                int ryo = po / 18;
                int rxo = po - ryo * 18;
                int gy = oy0 - 1 + ryo, gx = ox0 - 1 + rxo;
                half4 h = {(_Float16)0.f, (_Float16)0.f, (_Float16)0.f, (_Float16)0.f};
                if ((unsigned)gy < 1024u && (unsigned)gx < 1024u){
                    int yc = (gy == 0) ? 1 : ((gy == 1023) ? 2 : 0);
                    int xc = (gx == 0) ? 1 : ((gx == 1023) ? 2 : 0);
                    half4 u = *reinterpret_cast<const half4*>(
                        &U16[((size_t)(xc << 10) + gy) * 32 + cp]);
                    half4 v = *reinterpret_cast<const half4*>(
                        &V16[((size_t)(yc << 10) + gx) * 32 + cp]);
                    float4 k = *reinterpret_cast<const float4*>(&Kp[(yc * 3 + xc) * 32 + cp]);
                    h[0] = (_Float16)fmaxf((float)u[0] + (float)v[0] + k.x, 0.f);
                    h[1] = (_Float16)fmaxf((float)u[1] + (float)v[1] + k.y, 0.f);
                    h[2] = (_Float16)fmaxf((float)u[2] + (float)v[2] + k.z, 0.f);
                    h[3] = (_Float16)fmaxf((float)u[3] + (float)v[3] + k.w, 0.f);
                }
                *reinterpret_cast<half4*>(&ys[po * 32 + (cp ^ SWZ(rxo))]) = h;
            }
        }
    }
    __syncthreads();

    {
        half8 Bf[2][9];
        float bias[2], w3v[2];
        #pragma unroll
        for (int n = 0; n < 2; ++n){
            int co = n * 16 + lr;
            bias[n] = b2[co];
            w3v[n]  = w3[co];
            #pragma unroll
            for (int tap = 0; tap < 9; ++tap)
                Bf[n][tap] = *reinterpret_cast<const half8*>(
                    &wB[(tap * 32 + co) * 32 + ((lg * 8) ^ SWZ(co))]);
        }
        const float b3v = b3[0];
        for (int s = wid; s < 16; s += 8){
            int p  = s * 16 + lr;
            int ry = p >> 4;
            int rx = p & 15;
            f32x4 acc0 = {0.f, 0.f, 0.f, 0.f};
            f32x4 acc1 = {0.f, 0.f, 0.f, 0.f};
            #pragma unroll
            for (int tap = 0; tap < 9; ++tap){
                const int dy = tap / 3, dx = tap - (tap / 3) * 3;
                int pix = (ry + dy) * 18 + rx + dx;
                half8 A = *reinterpret_cast<const half8*>(
                    &ys[pix * 32 + ((lg * 8) ^ SWZ(rx + dx))]);
                acc0 = __builtin_amdgcn_mfma_f32_16x16x32_f16(A, Bf[0][tap], acc0, 0, 0, 0);
                acc1 = __builtin_amdgcn_mfma_f32_16x16x32_f16(A, Bf[1][tap], acc1, 0, 0, 0);
            }
            float part[4];
            #pragma unroll
            for (int j = 0; j < 4; ++j)
                part[j] = w3v[0] * fmaxf(acc0[j] + bias[0], 0.f)
                        + w3v[1] * fmaxf(acc1[j] + bias[1], 0.f);
            #pragma unroll
            for (int m = 1; m < 16; m <<= 1)
                #pragma unroll
                for (int j = 0; j < 4; ++j)
                    part[j] += __shfl_xor(part[j], m);
            if (lr == 0){
                float4 o = make_float4(part[0] + b3v, part[1] + b3v,
                                       part[2] + b3v, part[3] + b3v);
                *reinterpret_cast<float4*>(outp + (size_t)(oy0 + s) * 1024 + ox0 + lg * 4) = o;
            }
        }
    }
}

// ---------------------------------------------------------------------------
extern "C" void kernel_launch(void* const* d_in, const int* in_sizes, int n_in,
                              void* d_out, int out_size, void* d_ws, size_t ws_size,
                              hipStream_t stream)
{
    const float* lig_nf = (const float*)d_in[0];
    const float* lig_ef = (const float*)d_in[1];
    const float* rec_nf = (const float*)d_in[3];
    const float* rec_ef = (const float*)d_in[4];
    const float* Wn     = (const float*)d_in[6];
    const float* bn     = (const float*)d_in[7];
    const float* We     = (const float*)d_in[8];
    const float* be     = (const float*)d_in[9];
    const float* W_hopi = (const float*)d_in[12];
    const float* b_hopi = (const float*)d_in[13];
    const float* w1     = (const float*)d_in[14];
    const float* b1     = (const float*)d_in[15];
    const float* w2     = (const float*)d_in[16];
    const float* b2     = (const float*)d_in[17];
    const float* w3     = (const float*)d_in[18];
    const float* b3     = (const float*)d_in[19];
    float* outp = (float*)d_out;

    float* part  = (float*)d_ws;                              // [2][16][1024] f32
    short* Pw    = (short*)((char*)d_ws + 131072);            // [2][1024][32] f16
    float* cpart = (float*)((char*)d_ws + 262144);            // [16][32] f32
    float* Kp    = (float*)((char*)d_ws + 393216);            // 3*3*32 f32
    short* U16   = (short*)((char*)d_ws + 394368);            // 3*1024*32 f16
    short* V16   = (short*)((char*)d_ws + 590976);            // 3*1024*32 f16
    short* w2f16 = (short*)((char*)d_ws + 787584);            // 9216 f16 swizzled

    dim3 g1(8, 16, 2);
    gnn_kernel<<<g1, 512, 0, stream>>>(lig_nf, lig_ef, rec_nf, rec_ef,
                                       Wn, We, bn, be, part);
    pk_kernel<<<145, 512, 0, stream>>>(lig_nf, rec_nf, W_hopi, w2,
                                       part, Pw, cpart, w2f16);
    pp2_kernel<<<33, 512, 0, stream>>>(b_hopi, w1, b1, Pw, cpart,
                                       Kp, U16, V16);
    dim3 g3(64, 64);
    conv_kernel<<<g3, 512, 0, stream>>>(U16, V16, Kp, w2f16, b2, w3, b3, outp);
}